// Round 1
// baseline (1187.006 us; speedup 1.0000x reference)
//
#include <hip/hip_runtime.h>
#include <cstdint>
#include <cstddef>

// ---------------------------------------------------------------------------
// GraphSAGE 3-layer encoder.
// Reorder: agg(h) @ Wl == agg(h @ Wl)  (row-scaling by inv_deg commutes).
// Per layer: P = h@Wl ; Q = h@Wr + b ; out = act( inv_deg * segsum(P[src]) + Q )
// CSR built on-device each call (deterministic, no cached state).
// ---------------------------------------------------------------------------

// ---------- int64-vs-int32 edge index detection ----------
// If indices are int64 (little-endian, values < N), every high word is 0.
__global__ void k_detect(const int* __restrict__ ei, int* __restrict__ flag, int E) {
  int t = threadIdx.x;
  int stride = E / 4096; if (stride < 1) stride = 1;
  int found = 0;
  for (int i = t; i < 4096; i += 256) {
    long long e = (long long)i * stride;
    if (e < E && ei[2 * e + 1] != 0) found = 1;
  }
  if (found) atomicOr(flag, 1);
}

__device__ __forceinline__ int edge_val(const int* ei, int is64, size_t pos) {
  return is64 ? ei[2 * pos] : ei[pos];
}

// ---------- degree histogram over dst ----------
__global__ void k_hist(const int* __restrict__ ei, const int* __restrict__ flag,
                       int* __restrict__ cnt, int E) {
  int is64 = (*flag == 0);
  for (int e = blockIdx.x * blockDim.x + threadIdx.x; e < E;
       e += gridDim.x * blockDim.x) {
    int d = edge_val(ei, is64, (size_t)E + e);
    atomicAdd(&cnt[d], 1);
  }
}

// ---------- exclusive scan (3 kernels) ----------
__global__ void k_scan1(const int* __restrict__ cnt, int* __restrict__ row_start,
                        int* __restrict__ partials, int N) {
  __shared__ int sh[256];
  int t = threadIdx.x;
  int base = blockIdx.x * 1024;
  int idx0 = base + t * 4;
  int v[4]; int s = 0;
  #pragma unroll
  for (int i = 0; i < 4; i++) {
    int ix = idx0 + i;
    v[i] = (ix < N) ? cnt[ix] : 0;
    s += v[i];
  }
  sh[t] = s; __syncthreads();
  for (int off = 1; off < 256; off <<= 1) {
    int x = (t >= off) ? sh[t - off] : 0;
    __syncthreads();
    sh[t] += x;
    __syncthreads();
  }
  int excl = (t == 0) ? 0 : sh[t - 1];
  if (t == 255) partials[blockIdx.x] = sh[255];
  int run = excl;
  #pragma unroll
  for (int i = 0; i < 4; i++) {
    int ix = idx0 + i;
    if (ix < N) row_start[ix] = run;
    run += v[i];
  }
}

__global__ void k_scan2(int* __restrict__ partials, int nb) {
  __shared__ int sh[128];
  int t = threadIdx.x;
  int v = (t < nb) ? partials[t] : 0;
  sh[t] = v; __syncthreads();
  for (int off = 1; off < 128; off <<= 1) {
    int x = (t >= off) ? sh[t - off] : 0;
    __syncthreads();
    sh[t] += x;
    __syncthreads();
  }
  int excl = (t == 0) ? 0 : sh[t - 1];
  if (t < nb) partials[t] = excl;
}

__global__ void k_scan3(int* __restrict__ row_start, const int* __restrict__ partials,
                        int N, int E) {
  int i = blockIdx.x * 256 + threadIdx.x;
  if (i < N) row_start[i] += partials[i >> 10];
  if (i == 0) row_start[N] = E;
}

// ---------- scatter edges into CSR ----------
__global__ void k_scatter(const int* __restrict__ ei, const int* __restrict__ flag,
                          const int* __restrict__ row_start, int* __restrict__ cur,
                          int* __restrict__ sorted_src, int E) {
  int is64 = (*flag == 0);
  for (int e = blockIdx.x * blockDim.x + threadIdx.x; e < E;
       e += gridDim.x * blockDim.x) {
    int s = edge_val(ei, is64, (size_t)e);
    int d = edge_val(ei, is64, (size_t)E + e);
    int p = row_start[d] + atomicAdd(&cur[d], 1);
    sorted_src[p] = s;
  }
}

// ---------- f32 GEMM: out[M][H] = A[M][K] @ W[K][H] (+ bias) ----------
#define BM 128
#define BN 128
#define BKG 16

__global__ __launch_bounds__(256)
void k_gemm(const float* __restrict__ A, const float* __restrict__ W,
            const float* __restrict__ bias, float* __restrict__ out,
            int M, int K, int H) {
  __shared__ float AsT[BKG][BM];
  __shared__ float Bs[BKG][BN];
  int t = threadIdx.x;
  int tx = t & 15, ty = t >> 4;
  int m0 = blockIdx.y * BM;
  int n0 = blockIdx.x * BN;
  float acc[8][8];
  #pragma unroll
  for (int i = 0; i < 8; i++)
    #pragma unroll
    for (int j = 0; j < 8; j++) acc[i][j] = 0.f;

  int aRow = t >> 1;           // 0..127
  int aK   = (t & 1) * 8;      // 0 or 8
  int bK   = t >> 4;           // 0..15
  int bCol = (t & 15) * 8;     // 0..120

  for (int kt = 0; kt < K; kt += BKG) {
    {
      int gr = m0 + aRow;
      bool rok = gr < M;
      const float* ap = A + (size_t)gr * K + kt + aK;
      #pragma unroll
      for (int i = 0; i < 8; i++) {
        int k = kt + aK + i;
        AsT[aK + i][aRow] = (rok && k < K) ? ap[i] : 0.f;
      }
    }
    {
      int gk = kt + bK;
      bool kok = gk < K;
      const float* wp = W + (size_t)gk * H + n0 + bCol;
      #pragma unroll
      for (int i = 0; i < 8; i++) {
        int j = n0 + bCol + i;
        Bs[bK][bCol + i] = (kok && j < H) ? wp[i] : 0.f;
      }
    }
    __syncthreads();
    #pragma unroll
    for (int kk = 0; kk < BKG; ++kk) {
      float a[8], b[8];
      #pragma unroll
      for (int i = 0; i < 8; i++) a[i] = AsT[kk][ty * 8 + i];
      #pragma unroll
      for (int i = 0; i < 8; i++) b[i] = Bs[kk][tx * 8 + i];
      #pragma unroll
      for (int i = 0; i < 8; i++)
        #pragma unroll
        for (int j = 0; j < 8; j++)
          acc[i][j] += a[i] * b[j];
    }
    __syncthreads();
  }
  #pragma unroll
  for (int i = 0; i < 8; i++) {
    int r = m0 + ty * 8 + i;
    if (r >= M) continue;
    float* op = out + (size_t)r * H;
    #pragma unroll
    for (int j = 0; j < 8; j++) {
      int c = n0 + tx * 8 + j;
      if (c < H) op[c] = acc[i][j] + (bias ? bias[c] : 0.f);
    }
  }
}

// ---------- aggregation: out = act( scale * sum_{e} P[src_e] + Q ) ----------
// One wave per node; lane covers cols lane and lane+64.
// NOTE: Q and out may alias (element-wise in-place) -> no __restrict__ there.
template<int RELU>
__global__ void k_agg(const float* __restrict__ P, const float* Q,
                      const int* __restrict__ row_start, const int* __restrict__ srcs,
                      float* out, int N, int H) {
  int wave = threadIdx.x >> 6;
  int lane = threadIdx.x & 63;
  int node = blockIdx.x * 4 + wave;
  if (node >= N) return;
  int start = row_start[node], end = row_start[node + 1];
  int c0 = lane, c1 = lane + 64;
  float a0 = 0.f, a1 = 0.f;
  for (int e = start; e < end; ++e) {
    int s = srcs[e];
    const float* p = P + (size_t)s * H;
    a0 += p[c0];
    if (c1 < H) a1 += p[c1];
  }
  int deg = end - start;
  float scale = 1.f / (float)(deg > 0 ? deg : 1);
  size_t o = (size_t)node * H;
  float v0 = a0 * scale + Q[o + c0];
  if (RELU) v0 = fmaxf(v0, 0.f);
  out[o + c0] = v0;
  if (c1 < H) {
    float v1 = a1 * scale + Q[o + c1];
    if (RELU) v1 = fmaxf(v1, 0.f);
    out[o + c1] = v1;
  }
}

// ---------------------------------------------------------------------------
extern "C" void kernel_launch(void* const* d_in, const int* in_sizes, int n_in,
                              void* d_out, int out_size, void* d_ws, size_t ws_size,
                              hipStream_t stream) {
  const float* x   = (const float*)d_in[0];
  const int*   ei  = (const int*)d_in[1];
  const float* Wl1 = (const float*)d_in[2];
  const float* Wr1 = (const float*)d_in[3];
  const float* b1  = (const float*)d_in[4];
  const float* Wl2 = (const float*)d_in[5];
  const float* Wr2 = (const float*)d_in[6];
  const float* b2  = (const float*)d_in[7];
  const float* Wl3 = (const float*)d_in[8];
  const float* Wr3 = (const float*)d_in[9];
  const float* b3  = (const float*)d_in[10];

  const int DIN = 128;
  const int N  = in_sizes[0] / DIN;   // 100000
  const int E  = in_sizes[1] / 2;     // 1600000
  const int H1 = in_sizes[4];         // 128
  const int H2 = in_sizes[7];         // 76
  const int H3 = in_sizes[10];        // 64

  // ---- workspace carve ----
  char* w = (char*)d_ws;
  auto alloc = [&](size_t bytes) {
    char* p = w;
    w += (bytes + 255) & ~(size_t)255;
    return p;
  };
  float* bufA = (float*)alloc((size_t)N * 128 * 4);  // P buffers
  float* bufB = (float*)alloc((size_t)N * 128 * 4);  // Q1/h1, Q3
  float* bufC = (float*)alloc((size_t)N * 128 * 4);  // Q2/h2
  int* row_start = (int*)alloc((size_t)(N + 1) * 4);
  int* cnt       = (int*)alloc((size_t)N * 4);
  int* sorted    = (int*)alloc((size_t)E * 4);
  int* partials  = (int*)alloc(4096);
  int* flag      = (int*)alloc(256);

  // ---- CSR build ----
  hipMemsetAsync(flag, 0, 4, stream);
  k_detect<<<1, 256, 0, stream>>>(ei, flag, E);
  hipMemsetAsync(cnt, 0, (size_t)N * 4, stream);
  k_hist<<<2048, 256, 0, stream>>>(ei, flag, cnt, E);
  int nb1 = (N + 1023) / 1024;
  k_scan1<<<nb1, 256, 0, stream>>>(cnt, row_start, partials, N);
  k_scan2<<<1, 128, 0, stream>>>(partials, nb1);
  k_scan3<<<(N + 255) / 256, 256, 0, stream>>>(row_start, partials, N, E);
  hipMemsetAsync(cnt, 0, (size_t)N * 4, stream);
  k_scatter<<<2048, 256, 0, stream>>>(ei, flag, row_start, cnt, sorted, E);

  auto gemm = [&](const float* A, const float* W, const float* bias, float* out,
                  int M, int K, int H) {
    dim3 grid((H + BN - 1) / BN, (M + BM - 1) / BM);
    k_gemm<<<grid, 256, 0, stream>>>(A, W, bias, out, M, K, H);
  };
  int aggGrid = (N + 3) / 4;

  // ---- layer 1 (relu) ----
  gemm(x, Wl1, nullptr, bufA, N, DIN, H1);
  gemm(x, Wr1, b1, bufB, N, DIN, H1);
  k_agg<1><<<aggGrid, 256, 0, stream>>>(bufA, bufB, row_start, sorted, bufB, N, H1);

  // ---- layer 2 (relu) ----
  gemm(bufB, Wl2, nullptr, bufA, N, H1, H2);
  gemm(bufB, Wr2, b2, bufC, N, H1, H2);
  k_agg<1><<<aggGrid, 256, 0, stream>>>(bufA, bufC, row_start, sorted, bufC, N, H2);

  // ---- layer 3 (linear) ----
  gemm(bufC, Wl3, nullptr, bufA, N, H2, H3);
  gemm(bufC, Wr3, b3, bufB, N, H2, H3);
  k_agg<0><<<aggGrid, 256, 0, stream>>>(bufA, bufB, row_start, sorted,
                                        (float*)d_out, N, H3);
}

// Round 2
// 852.489 us; speedup vs baseline: 1.3924x; 1.3924x over previous
//
#include <hip/hip_runtime.h>
#include <hip/hip_bf16.h>
#include <cstdint>
#include <cstddef>

// ---------------------------------------------------------------------------
// GraphSAGE 3-layer encoder.
// Reorder: agg(h) @ Wl == agg(h @ Wl)  (row-scaling by inv_deg commutes).
// Per layer: P = bf16(h@Wl) ; Q = h@Wr + b ; out = act(inv_deg*segsum(P[src]) + Q)
// CSR built on-device each call (deterministic, no cached state).
// ---------------------------------------------------------------------------

// ---------- int64-vs-int32 edge index detection ----------
__global__ void k_detect(const int* __restrict__ ei, int* __restrict__ flag, int E) {
  int t = threadIdx.x;
  int stride = E / 4096; if (stride < 1) stride = 1;
  int found = 0;
  for (int i = t; i < 4096; i += 256) {
    long long e = (long long)i * stride;
    if (e < E && ei[2 * e + 1] != 0) found = 1;
  }
  if (found) atomicOr(flag, 1);
}

__device__ __forceinline__ int edge_val(const int* ei, int is64, size_t pos) {
  return is64 ? ei[2 * pos] : ei[pos];
}

// ---------- degree histogram over dst ----------
__global__ void k_hist(const int* __restrict__ ei, const int* __restrict__ flag,
                       int* __restrict__ cnt, int E) {
  int is64 = (*flag == 0);
  for (int e = blockIdx.x * blockDim.x + threadIdx.x; e < E;
       e += gridDim.x * blockDim.x) {
    int d = edge_val(ei, is64, (size_t)E + e);
    atomicAdd(&cnt[d], 1);
  }
}

// ---------- exclusive scan (3 kernels) ----------
__global__ void k_scan1(const int* __restrict__ cnt, int* __restrict__ row_start,
                        int* __restrict__ partials, int N) {
  __shared__ int sh[256];
  int t = threadIdx.x;
  int base = blockIdx.x * 1024;
  int idx0 = base + t * 4;
  int v[4]; int s = 0;
  #pragma unroll
  for (int i = 0; i < 4; i++) {
    int ix = idx0 + i;
    v[i] = (ix < N) ? cnt[ix] : 0;
    s += v[i];
  }
  sh[t] = s; __syncthreads();
  for (int off = 1; off < 256; off <<= 1) {
    int x = (t >= off) ? sh[t - off] : 0;
    __syncthreads();
    sh[t] += x;
    __syncthreads();
  }
  int excl = (t == 0) ? 0 : sh[t - 1];
  if (t == 255) partials[blockIdx.x] = sh[255];
  int run = excl;
  #pragma unroll
  for (int i = 0; i < 4; i++) {
    int ix = idx0 + i;
    if (ix < N) row_start[ix] = run;
    run += v[i];
  }
}

__global__ void k_scan2(int* __restrict__ partials, int nb) {
  __shared__ int sh[128];
  int t = threadIdx.x;
  int v = (t < nb) ? partials[t] : 0;
  sh[t] = v; __syncthreads();
  for (int off = 1; off < 128; off <<= 1) {
    int x = (t >= off) ? sh[t - off] : 0;
    __syncthreads();
    sh[t] += x;
    __syncthreads();
  }
  int excl = (t == 0) ? 0 : sh[t - 1];
  if (t < nb) partials[t] = excl;
}

__global__ void k_scan3(int* __restrict__ row_start, const int* __restrict__ partials,
                        int N, int E) {
  int i = blockIdx.x * 256 + threadIdx.x;
  if (i < N) row_start[i] += partials[i >> 10];
  if (i == 0) row_start[N] = E;
}

// ---------- scatter edges into CSR ----------
__global__ void k_scatter(const int* __restrict__ ei, const int* __restrict__ flag,
                          const int* __restrict__ row_start, int* __restrict__ cur,
                          int* __restrict__ sorted_src, int E) {
  int is64 = (*flag == 0);
  for (int e = blockIdx.x * blockDim.x + threadIdx.x; e < E;
       e += gridDim.x * blockDim.x) {
    int s = edge_val(ei, is64, (size_t)e);
    int d = edge_val(ei, is64, (size_t)E + e);
    int p = row_start[d] + atomicAdd(&cur[d], 1);
    sorted_src[p] = s;
  }
}

// ---------- f32 GEMM: out[M][H] = A[M][K] @ W[K][H] (+ bias) ----------
// BF16OUT: write output rounded to bf16 (for the Wl/gather path).
#define BM 128
#define BN 128
#define BKG 16

template<bool BF16OUT>
__global__ __launch_bounds__(256)
void k_gemm(const float* __restrict__ A, const float* __restrict__ W,
            const float* __restrict__ bias, void* __restrict__ outv,
            int M, int K, int H) {
  __shared__ float AsT[BKG][BM];
  __shared__ float Bs[BKG][BN];
  int t = threadIdx.x;
  int tx = t & 15, ty = t >> 4;
  int m0 = blockIdx.y * BM;
  int n0 = blockIdx.x * BN;
  float acc[8][8];
  #pragma unroll
  for (int i = 0; i < 8; i++)
    #pragma unroll
    for (int j = 0; j < 8; j++) acc[i][j] = 0.f;

  int aRow = t >> 1;           // 0..127
  int aK   = (t & 1) * 8;      // 0 or 8
  int bK   = t >> 4;           // 0..15
  int bCol = (t & 15) * 8;     // 0..120

  for (int kt = 0; kt < K; kt += BKG) {
    {
      int gr = m0 + aRow;
      bool rok = gr < M;
      const float* ap = A + (size_t)gr * K + kt + aK;
      #pragma unroll
      for (int i = 0; i < 8; i++) {
        int k = kt + aK + i;
        AsT[aK + i][aRow] = (rok && k < K) ? ap[i] : 0.f;
      }
    }
    {
      int gk = kt + bK;
      bool kok = gk < K;
      const float* wp = W + (size_t)gk * H + n0 + bCol;
      #pragma unroll
      for (int i = 0; i < 8; i++) {
        int j = n0 + bCol + i;
        Bs[bK][bCol + i] = (kok && j < H) ? wp[i] : 0.f;
      }
    }
    __syncthreads();
    #pragma unroll
    for (int kk = 0; kk < BKG; ++kk) {
      float a[8], b[8];
      #pragma unroll
      for (int i = 0; i < 8; i++) a[i] = AsT[kk][ty * 8 + i];
      #pragma unroll
      for (int i = 0; i < 8; i++) b[i] = Bs[kk][tx * 8 + i];
      #pragma unroll
      for (int i = 0; i < 8; i++)
        #pragma unroll
        for (int j = 0; j < 8; j++)
          acc[i][j] += a[i] * b[j];
    }
    __syncthreads();
  }
  #pragma unroll
  for (int i = 0; i < 8; i++) {
    int r = m0 + ty * 8 + i;
    if (r >= M) continue;
    #pragma unroll
    for (int j = 0; j < 8; j++) {
      int c = n0 + tx * 8 + j;
      if (c >= H) continue;
      float v = acc[i][j] + (bias ? bias[c] : 0.f);
      if (BF16OUT)
        ((__hip_bfloat16*)outv)[(size_t)r * H + c] = __float2bfloat16(v);
      else
        ((float*)outv)[(size_t)r * H + c] = v;
    }
  }
}

// ---------- aggregation: out = act( scale * sum_{e} bf16 P[src_e] + Q ) ----------
// One wave per node. Edge indices coalesce-loaded into lanes, broadcast by shfl.
// 4-deep unroll -> 4 outstanding row gathers. PACK=2: lane covers cols {2l,2l+1}
// via one bf16x2 (4B) load; PACK=1: lane covers col l via 2B load (H<=64).
__device__ __forceinline__ float bflo(uint32_t u) {
  union { uint32_t i; float f; } v; v.i = u << 16; return v.f;
}
__device__ __forceinline__ float bfhi(uint32_t u) {
  union { uint32_t i; float f; } v; v.i = u & 0xffff0000u; return v.f;
}

template<int RELU, int PACK>
__global__ __launch_bounds__(256)
void k_agg(const __hip_bfloat16* __restrict__ P, const float* Q,
           const int* __restrict__ rs, const int* __restrict__ srcs,
           float* out, int N, int H) {
  int wave = threadIdx.x >> 6;
  int lane = threadIdx.x & 63;
  int node = blockIdx.x * 4 + wave;
  if (node >= N) return;
  int start = rs[node];
  int deg = rs[node + 1] - start;
  int c = lane * PACK;
  bool act = c < H;
  float a0 = 0.f, a1 = 0.f;
  const int* sp = srcs + start;

  for (int base = 0; base < deg; base += 64) {
    int cnt = deg - base; if (cnt > 64) cnt = 64;
    int myidx = (lane < cnt) ? sp[base + lane] : 0;
    int e = 0;
    int nfull = cnt & ~3;
    for (; e < nfull; e += 4) {
      int s0 = __shfl(myidx, e);
      int s1 = __shfl(myidx, e + 1);
      int s2 = __shfl(myidx, e + 2);
      int s3 = __shfl(myidx, e + 3);
      if (act) {
        if (PACK == 2) {
          uint32_t u0 = *(const uint32_t*)(P + (size_t)s0 * H + c);
          uint32_t u1 = *(const uint32_t*)(P + (size_t)s1 * H + c);
          uint32_t u2 = *(const uint32_t*)(P + (size_t)s2 * H + c);
          uint32_t u3 = *(const uint32_t*)(P + (size_t)s3 * H + c);
          a0 += bflo(u0); a1 += bfhi(u0);
          a0 += bflo(u1); a1 += bfhi(u1);
          a0 += bflo(u2); a1 += bfhi(u2);
          a0 += bflo(u3); a1 += bfhi(u3);
        } else {
          uint32_t u0 = *(const uint16_t*)(P + (size_t)s0 * H + c);
          uint32_t u1 = *(const uint16_t*)(P + (size_t)s1 * H + c);
          uint32_t u2 = *(const uint16_t*)(P + (size_t)s2 * H + c);
          uint32_t u3 = *(const uint16_t*)(P + (size_t)s3 * H + c);
          a0 += bflo(u0) + bflo(u1) + bflo(u2) + bflo(u3);
        }
      }
    }
    for (; e < cnt; ++e) {
      int s0 = __shfl(myidx, e);
      if (act) {
        if (PACK == 2) {
          uint32_t u0 = *(const uint32_t*)(P + (size_t)s0 * H + c);
          a0 += bflo(u0); a1 += bfhi(u0);
        } else {
          uint32_t u0 = *(const uint16_t*)(P + (size_t)s0 * H + c);
          a0 += bflo(u0);
        }
      }
    }
  }

  if (!act) return;
  float scale = 1.f / (float)(deg > 0 ? deg : 1);
  size_t o = (size_t)node * H + c;
  if (PACK == 2) {
    float2 q = *(const float2*)(Q + o);
    float v0 = a0 * scale + q.x;
    float v1 = a1 * scale + q.y;
    if (RELU) { v0 = fmaxf(v0, 0.f); v1 = fmaxf(v1, 0.f); }
    float2 r; r.x = v0; r.y = v1;
    *(float2*)(out + o) = r;
  } else {
    float v0 = a0 * scale + Q[o];
    if (RELU) v0 = fmaxf(v0, 0.f);
    out[o] = v0;
  }
}

// ---------------------------------------------------------------------------
extern "C" void kernel_launch(void* const* d_in, const int* in_sizes, int n_in,
                              void* d_out, int out_size, void* d_ws, size_t ws_size,
                              hipStream_t stream) {
  const float* x   = (const float*)d_in[0];
  const int*   ei  = (const int*)d_in[1];
  const float* Wl1 = (const float*)d_in[2];
  const float* Wr1 = (const float*)d_in[3];
  const float* b1  = (const float*)d_in[4];
  const float* Wl2 = (const float*)d_in[5];
  const float* Wr2 = (const float*)d_in[6];
  const float* b2  = (const float*)d_in[7];
  const float* Wl3 = (const float*)d_in[8];
  const float* Wr3 = (const float*)d_in[9];
  const float* b3  = (const float*)d_in[10];

  const int DIN = 128;
  const int N  = in_sizes[0] / DIN;   // 100000
  const int E  = in_sizes[1] / 2;     // 1600000
  const int H1 = in_sizes[4];         // 128
  const int H2 = in_sizes[7];         // 76
  const int H3 = in_sizes[10];        // 64

  // ---- workspace carve ----
  char* w = (char*)d_ws;
  auto alloc = [&](size_t bytes) {
    char* p = w;
    w += (bytes + 255) & ~(size_t)255;
    return p;
  };
  __hip_bfloat16* bufP = (__hip_bfloat16*)alloc((size_t)N * 128 * 2);  // P (bf16)
  float* bufB = (float*)alloc((size_t)N * 128 * 4);  // Q1/h1, Q3
  float* bufC = (float*)alloc((size_t)N * 128 * 4);  // Q2/h2
  int* row_start = (int*)alloc((size_t)(N + 1) * 4);
  int* cnt       = (int*)alloc((size_t)N * 4);
  int* sorted    = (int*)alloc((size_t)E * 4);
  int* partials  = (int*)alloc(4096);
  int* flag      = (int*)alloc(256);

  // ---- CSR build ----
  hipMemsetAsync(flag, 0, 4, stream);
  k_detect<<<1, 256, 0, stream>>>(ei, flag, E);
  hipMemsetAsync(cnt, 0, (size_t)N * 4, stream);
  k_hist<<<2048, 256, 0, stream>>>(ei, flag, cnt, E);
  int nb1 = (N + 1023) / 1024;
  k_scan1<<<nb1, 256, 0, stream>>>(cnt, row_start, partials, N);
  k_scan2<<<1, 128, 0, stream>>>(partials, nb1);
  k_scan3<<<(N + 255) / 256, 256, 0, stream>>>(row_start, partials, N, E);
  hipMemsetAsync(cnt, 0, (size_t)N * 4, stream);
  k_scatter<<<2048, 256, 0, stream>>>(ei, flag, row_start, cnt, sorted, E);

  auto gemm_f32 = [&](const float* A, const float* W, const float* bias, float* out,
                      int M, int K, int H) {
    dim3 grid((H + BN - 1) / BN, (M + BM - 1) / BM);
    k_gemm<false><<<grid, 256, 0, stream>>>(A, W, bias, (void*)out, M, K, H);
  };
  auto gemm_bf16 = [&](const float* A, const float* W, __hip_bfloat16* out,
                       int M, int K, int H) {
    dim3 grid((H + BN - 1) / BN, (M + BM - 1) / BM);
    k_gemm<true><<<grid, 256, 0, stream>>>(A, W, nullptr, (void*)out, M, K, H);
  };
  int aggGrid = (N + 3) / 4;

  // ---- layer 1 (relu) ----
  gemm_bf16(x, Wl1, bufP, N, DIN, H1);
  gemm_f32 (x, Wr1, b1, bufB, N, DIN, H1);
  k_agg<1, 2><<<aggGrid, 256, 0, stream>>>(bufP, bufB, row_start, sorted, bufB, N, H1);

  // ---- layer 2 (relu) ----
  gemm_bf16(bufB, Wl2, bufP, N, H1, H2);
  gemm_f32 (bufB, Wr2, b2, bufC, N, H1, H2);
  k_agg<1, 2><<<aggGrid, 256, 0, stream>>>(bufP, bufC, row_start, sorted, bufC, N, H2);

  // ---- layer 3 (linear) ----
  gemm_bf16(bufC, Wl3, bufP, N, H2, H3);
  gemm_f32 (bufC, Wr3, b3, bufB, N, H2, H3);
  k_agg<0, 1><<<aggGrid, 256, 0, stream>>>(bufP, bufB, row_start, sorted,
                                           (float*)d_out, N, H3);
}

// Round 3
// 585.421 us; speedup vs baseline: 2.0276x; 1.4562x over previous
//
#include <hip/hip_runtime.h>
#include <hip/hip_bf16.h>
#include <cstdint>
#include <cstddef>

// ---------------------------------------------------------------------------
// GraphSAGE 3-layer encoder, MFMA edition.
// Per layer (fused): [P | Q] = A @ [Wl | Wr]  via bf16 MFMA (f32 accum)
//   P -> bf16 (gather operand), Q -> f32 (+bias)
//   out = act( inv_deg * segsum(P[src]) + Q )   (bf16 for hidden layers)
// CSR built on-device each call.
// ---------------------------------------------------------------------------

typedef __attribute__((ext_vector_type(8))) short bf16x8;
typedef __attribute__((ext_vector_type(4))) float f32x4;

__device__ __forceinline__ short f2bf(float f) {
  uint32_t u = __builtin_bit_cast(uint32_t, f);
  u += 0x7fffu + ((u >> 16) & 1u);
  return (short)(u >> 16);
}
__device__ __forceinline__ float bflo(uint32_t u) {
  union { uint32_t i; float f; } v; v.i = u << 16; return v.f;
}
__device__ __forceinline__ float bfhi(uint32_t u) {
  union { uint32_t i; float f; } v; v.i = u & 0xffff0000u; return v.f;
}

// ---------- int64-vs-int32 edge index detection ----------
__global__ void k_detect(const int* __restrict__ ei, int* __restrict__ flag, int E) {
  int t = threadIdx.x;
  int stride = E / 4096; if (stride < 1) stride = 1;
  int found = 0;
  for (int i = t; i < 4096; i += 256) {
    long long e = (long long)i * stride;
    if (e < E && ei[2 * e + 1] != 0) found = 1;
  }
  if (found) atomicOr(flag, 1);
}

__device__ __forceinline__ int edge_val(const int* ei, int is64, size_t pos) {
  return is64 ? ei[2 * pos] : ei[pos];
}

// ---------- degree histogram over dst ----------
__global__ void k_hist(const int* __restrict__ ei, const int* __restrict__ flag,
                       int* __restrict__ cnt, int E) {
  int is64 = (*flag == 0);
  for (int e = blockIdx.x * blockDim.x + threadIdx.x; e < E;
       e += gridDim.x * blockDim.x) {
    int d = edge_val(ei, is64, (size_t)E + e);
    atomicAdd(&cnt[d], 1);
  }
}

// ---------- exclusive scan (3 kernels) ----------
__global__ void k_scan1(const int* __restrict__ cnt, int* __restrict__ row_start,
                        int* __restrict__ partials, int N) {
  __shared__ int sh[256];
  int t = threadIdx.x;
  int base = blockIdx.x * 1024;
  int idx0 = base + t * 4;
  int v[4]; int s = 0;
  #pragma unroll
  for (int i = 0; i < 4; i++) {
    int ix = idx0 + i;
    v[i] = (ix < N) ? cnt[ix] : 0;
    s += v[i];
  }
  sh[t] = s; __syncthreads();
  for (int off = 1; off < 256; off <<= 1) {
    int x = (t >= off) ? sh[t - off] : 0;
    __syncthreads();
    sh[t] += x;
    __syncthreads();
  }
  int excl = (t == 0) ? 0 : sh[t - 1];
  if (t == 255) partials[blockIdx.x] = sh[255];
  int run = excl;
  #pragma unroll
  for (int i = 0; i < 4; i++) {
    int ix = idx0 + i;
    if (ix < N) row_start[ix] = run;
    run += v[i];
  }
}

__global__ void k_scan2(int* __restrict__ partials, int nb) {
  __shared__ int sh[128];
  int t = threadIdx.x;
  int v = (t < nb) ? partials[t] : 0;
  sh[t] = v; __syncthreads();
  for (int off = 1; off < 128; off <<= 1) {
    int x = (t >= off) ? sh[t - off] : 0;
    __syncthreads();
    sh[t] += x;
    __syncthreads();
  }
  int excl = (t == 0) ? 0 : sh[t - 1];
  if (t < nb) partials[t] = excl;
}

__global__ void k_scan3(int* __restrict__ row_start, const int* __restrict__ partials,
                        int N, int E) {
  int i = blockIdx.x * 256 + threadIdx.x;
  if (i < N) row_start[i] += partials[i >> 10];
  if (i == 0) row_start[N] = E;
}

// ---------- scatter edges into CSR (cur pre-initialized to row_start) -------
__global__ void k_scatter(const int* __restrict__ ei, const int* __restrict__ flag,
                          int* __restrict__ cur, int* __restrict__ sorted_src, int E) {
  int is64 = (*flag == 0);
  for (int e = blockIdx.x * blockDim.x + threadIdx.x; e < E;
       e += gridDim.x * blockDim.x) {
    int s = edge_val(ei, is64, (size_t)e);
    int d = edge_val(ei, is64, (size_t)E + e);
    int p = atomicAdd(&cur[d], 1);
    sorted_src[p] = s;
  }
}

// ---------- weight prep: Wt[c][k] (bf16, transposed, zero-padded) ----------
// c in [0,Hp): Wl col c ; c in [Hp, 2Hp): Wr col c-Hp ; zero padding elsewhere.
__global__ void k_wprep(const float* __restrict__ Wl, const float* __restrict__ Wr,
                        short* __restrict__ Wt, int K, int H, int Hp, int Kp, int NP) {
  int idx = blockIdx.x * 256 + threadIdx.x;
  if (idx >= NP * Kp) return;
  int c = idx / Kp, k = idx - c * Kp;
  float v = 0.f;
  if (k < K) {
    if (c < H) v = Wl[(size_t)k * H + c];
    else if (c >= Hp && c - Hp < H) v = Wr[(size_t)k * H + (c - Hp)];
  }
  Wt[idx] = f2bf(v);
}

// ---------- fused MFMA GEMM: [P|Q] = A @ Wt^T ----------
// MODE 0: A f32 (cvt on stage). MODE 1: A bf16, K%4==0. MODE 2: A bf16, K=76.
// NKS: K-steps of 32 (Kp = NKS*32). Block: 256 thr, BM=128 rows, waves split cols.
#define PK 136   // LDS row stride (shorts): Kp<=128 plus 8 pad

template<int MODE, int NKS>
__global__ __launch_bounds__(256)
void k_gemm_mfma(const void* __restrict__ Av, const short* __restrict__ Wt,
                 const float* __restrict__ bias, short* __restrict__ P,
                 float* __restrict__ Q, int M, int K, int H, int Hp, int NP) {
  __shared__ short As[128][PK];
  const int Kp = NKS * 32;
  int t = threadIdx.x;
  int m0 = blockIdx.x * 128;

  // ---- stage A tile (128 x Kp bf16), zero-padded ----
  if (MODE == 0) {
    const float* A = (const float*)Av;
    for (int idx = t; idx < 128 * (128 / 4); idx += 256) {
      int row = idx >> 5, c4 = (idx & 31) << 2;
      int gr = m0 + row;
      float4 v = make_float4(0.f, 0.f, 0.f, 0.f);
      if (gr < M) v = *(const float4*)(A + (size_t)gr * K + c4);
      uint2 pk;
      pk.x = (uint32_t)(uint16_t)f2bf(v.x) | ((uint32_t)(uint16_t)f2bf(v.y) << 16);
      pk.y = (uint32_t)(uint16_t)f2bf(v.z) | ((uint32_t)(uint16_t)f2bf(v.w) << 16);
      *(uint2*)&As[row][c4] = pk;
    }
  } else if (MODE == 1) {
    const short* A = (const short*)Av;
    for (int idx = t; idx < 128 * (128 / 4); idx += 256) {
      int row = idx >> 5, c4 = (idx & 31) << 2;
      int gr = m0 + row;
      uint2 v = make_uint2(0u, 0u);
      if (gr < M) v = *(const uint2*)(A + (size_t)gr * K + c4);
      *(uint2*)&As[row][c4] = v;
    }
  } else {
    const short* A = (const short*)Av;
    for (int idx = t; idx < 128 * 48; idx += 256) {  // Kp=96 -> 48 uint chunks/row
      int row = idx / 48, c2 = idx - row * 48;
      int k = c2 * 2;
      int gr = m0 + row;
      uint32_t v = 0u;
      if (gr < M && k < K) v = *(const uint32_t*)(A + (size_t)gr * K + k);
      *(uint32_t*)&As[row][k] = v;
    }
  }

  // ---- per-wave column split + B-frags to registers ----
  int wv = __builtin_amdgcn_readfirstlane(t >> 6);
  int lane = t & 63;
  int ncf_total = NP >> 4;
  int qd = ncf_total >> 2, rm = ncf_total & 3;
  int cf0 = wv * qd + (wv < rm ? wv : rm);
  int myncf = qd + (wv < rm ? 1 : 0);

  int lrow = lane & 15;          // A row / D col within frag
  int lk8 = (lane >> 4) * 8;     // k sub-offset

  bf16x8 b[4][NKS];
  #pragma unroll
  for (int cf = 0; cf < 4; cf++) {
    if (cf < myncf) {
      int col = (cf0 + cf) * 16 + lrow;
      #pragma unroll
      for (int ks = 0; ks < NKS; ks++)
        b[cf][ks] = *(const bf16x8*)(Wt + (size_t)col * Kp + ks * 32 + lk8);
    }
  }

  __syncthreads();

  // ---- K-loop over 8 row-frags ----
  for (int rf = 0; rf < 8; ++rf) {
    bf16x8 a[NKS];
    #pragma unroll
    for (int ks = 0; ks < NKS; ks++)
      a[ks] = *(const bf16x8*)&As[rf * 16 + lrow][ks * 32 + lk8];
    f32x4 acc[4];
    #pragma unroll
    for (int cf = 0; cf < 4; cf++) acc[cf] = (f32x4){0.f, 0.f, 0.f, 0.f};
    #pragma unroll
    for (int ks = 0; ks < NKS; ks++) {
      #pragma unroll
      for (int cf = 0; cf < 4; cf++) {
        if (cf < myncf)
          acc[cf] = __builtin_amdgcn_mfma_f32_16x16x32_bf16(a[ks], b[cf][ks], acc[cf], 0, 0, 0);
      }
    }
    // ---- epilogue for this row-frag ----
    int r0 = m0 + rf * 16 + (lane >> 4) * 4;
    #pragma unroll
    for (int cf = 0; cf < 4; cf++) {
      if (cf < myncf) {
        int c = (cf0 + cf) * 16 + lrow;
        bool isP = c < Hp;
        int cc = isP ? c : c - Hp;
        if (cc < H) {
          #pragma unroll
          for (int rg = 0; rg < 4; rg++) {
            int rr = r0 + rg;
            if (rr < M) {
              float v = acc[cf][rg];
              if (isP) P[(size_t)rr * H + cc] = f2bf(v);
              else     Q[(size_t)rr * H + cc] = v + bias[cc];
            }
          }
        }
      }
    }
  }
}

// ---------- aggregation: out = act( scale * sum_{e} bf16 P[src_e] + Q ) ------
template<int RELU, int PACK, int OUTBF16>
__global__ __launch_bounds__(256)
void k_agg(const short* __restrict__ P, const float* Q,
           const int* __restrict__ rs, const int* __restrict__ srcs,
           void* out, int N, int H) {
  int wave = threadIdx.x >> 6;
  int lane = threadIdx.x & 63;
  int node = blockIdx.x * 4 + wave;
  if (node >= N) return;
  int start = rs[node];
  int deg = rs[node + 1] - start;
  int c = lane * PACK;
  bool act = c < H;
  float a0 = 0.f, a1 = 0.f;
  const int* sp = srcs + start;

  for (int base = 0; base < deg; base += 64) {
    int cnt = deg - base; if (cnt > 64) cnt = 64;
    int myidx = (lane < cnt) ? sp[base + lane] : 0;
    int e = 0;
    int nfull = cnt & ~3;
    for (; e < nfull; e += 4) {
      int s0 = __shfl(myidx, e);
      int s1 = __shfl(myidx, e + 1);
      int s2 = __shfl(myidx, e + 2);
      int s3 = __shfl(myidx, e + 3);
      if (act) {
        if (PACK == 2) {
          uint32_t u0 = *(const uint32_t*)(P + (size_t)s0 * H + c);
          uint32_t u1 = *(const uint32_t*)(P + (size_t)s1 * H + c);
          uint32_t u2 = *(const uint32_t*)(P + (size_t)s2 * H + c);
          uint32_t u3 = *(const uint32_t*)(P + (size_t)s3 * H + c);
          a0 += bflo(u0); a1 += bfhi(u0);
          a0 += bflo(u1); a1 += bfhi(u1);
          a0 += bflo(u2); a1 += bfhi(u2);
          a0 += bflo(u3); a1 += bfhi(u3);
        } else {
          uint32_t u0 = *(const uint16_t*)(P + (size_t)s0 * H + c);
          uint32_t u1 = *(const uint16_t*)(P + (size_t)s1 * H + c);
          uint32_t u2 = *(const uint16_t*)(P + (size_t)s2 * H + c);
          uint32_t u3 = *(const uint16_t*)(P + (size_t)s3 * H + c);
          a0 += bflo(u0) + bflo(u1) + bflo(u2) + bflo(u3);
        }
      }
    }
    for (; e < cnt; ++e) {
      int s0 = __shfl(myidx, e);
      if (act) {
        if (PACK == 2) {
          uint32_t u0 = *(const uint32_t*)(P + (size_t)s0 * H + c);
          a0 += bflo(u0); a1 += bfhi(u0);
        } else {
          uint32_t u0 = *(const uint16_t*)(P + (size_t)s0 * H + c);
          a0 += bflo(u0);
        }
      }
    }
  }

  if (!act) return;
  float scale = 1.f / (float)(deg > 0 ? deg : 1);
  size_t o = (size_t)node * H + c;
  if (PACK == 2) {
    float2 q = *(const float2*)(Q + o);
    float v0 = a0 * scale + q.x;
    float v1 = a1 * scale + q.y;
    if (RELU) { v0 = fmaxf(v0, 0.f); v1 = fmaxf(v1, 0.f); }
    if (OUTBF16) {
      uint32_t pk = (uint32_t)(uint16_t)f2bf(v0) | ((uint32_t)(uint16_t)f2bf(v1) << 16);
      *(uint32_t*)((short*)out + o) = pk;
    } else {
      float2 r; r.x = v0; r.y = v1;
      *(float2*)((float*)out + o) = r;
    }
  } else {
    float v0 = a0 * scale + Q[o];
    if (RELU) v0 = fmaxf(v0, 0.f);
    if (OUTBF16) ((short*)out)[o] = f2bf(v0);
    else ((float*)out)[o] = v0;
  }
}

// ---------------------------------------------------------------------------
extern "C" void kernel_launch(void* const* d_in, const int* in_sizes, int n_in,
                              void* d_out, int out_size, void* d_ws, size_t ws_size,
                              hipStream_t stream) {
  const float* x   = (const float*)d_in[0];
  const int*   ei  = (const int*)d_in[1];
  const float* Wl1 = (const float*)d_in[2];
  const float* Wr1 = (const float*)d_in[3];
  const float* b1  = (const float*)d_in[4];
  const float* Wl2 = (const float*)d_in[5];
  const float* Wr2 = (const float*)d_in[6];
  const float* b2  = (const float*)d_in[7];
  const float* Wl3 = (const float*)d_in[8];
  const float* Wr3 = (const float*)d_in[9];
  const float* b3  = (const float*)d_in[10];

  const int DIN = 128;
  const int N  = in_sizes[0] / DIN;   // 100000
  const int E  = in_sizes[1] / 2;     // 1600000
  const int H1 = in_sizes[4];         // 128
  const int H2 = in_sizes[7];         // 76
  const int H3 = in_sizes[10];        // 64
  const int Hp1 = 128, Hp2 = 80, Hp3 = 64;
  const int Kp12 = 128, Kp3 = 96;

  // ---- workspace carve ----
  char* w = (char*)d_ws;
  auto alloc = [&](size_t bytes) {
    char* p = w;
    w += (bytes + 255) & ~(size_t)255;
    return p;
  };
  short* bufP  = (short*)alloc((size_t)N * 128 * 2);   // P (bf16)
  short* bufH1 = (short*)alloc((size_t)N * 128 * 2);   // h1 (bf16)
  short* bufH2 = (short*)alloc((size_t)N * 80 * 2);    // h2 (bf16, stride 76)
  float* bufB  = (float*)alloc((size_t)N * 128 * 4);   // Q1 / Q3 (f32)
  float* bufC  = (float*)alloc((size_t)N * 80 * 4);    // Q2 (f32, stride 76)
  short* Wt1   = (short*)alloc((size_t)256 * 128 * 2);
  short* Wt2   = (short*)alloc((size_t)160 * 128 * 2);
  short* Wt3   = (short*)alloc((size_t)128 * 96 * 2);
  int* row_start = (int*)alloc((size_t)(N + 1) * 4);
  int* cur       = (int*)alloc((size_t)N * 4);
  int* sorted    = (int*)alloc((size_t)E * 4);
  int* partials  = (int*)alloc(4096);
  int* flag      = (int*)alloc(256);

  // ---- weight prep ----
  k_wprep<<<(256 * 128 + 255) / 256, 256, 0, stream>>>(Wl1, Wr1, Wt1, DIN, H1, Hp1, Kp12, 2 * Hp1);
  k_wprep<<<(160 * 128 + 255) / 256, 256, 0, stream>>>(Wl2, Wr2, Wt2, H1, H2, Hp2, Kp12, 2 * Hp2);
  k_wprep<<<(128 * 96 + 255) / 256, 256, 0, stream>>>(Wl3, Wr3, Wt3, H2, H3, Hp3, Kp3, 2 * Hp3);

  // ---- CSR build ----
  hipMemsetAsync(flag, 0, 4, stream);
  k_detect<<<1, 256, 0, stream>>>(ei, flag, E);
  hipMemsetAsync(cur, 0, (size_t)N * 4, stream);
  k_hist<<<2048, 256, 0, stream>>>(ei, flag, cur, E);
  int nb1 = (N + 1023) / 1024;
  k_scan1<<<nb1, 256, 0, stream>>>(cur, row_start, partials, N);
  k_scan2<<<1, 128, 0, stream>>>(partials, nb1);
  k_scan3<<<(N + 255) / 256, 256, 0, stream>>>(row_start, partials, N, E);
  hipMemcpyAsync(cur, row_start, (size_t)N * 4, hipMemcpyDeviceToDevice, stream);
  k_scatter<<<2048, 256, 0, stream>>>(ei, flag, cur, sorted, E);

  int gemmGrid = (N + 127) / 128;
  int aggGrid = (N + 3) / 4;

  // ---- layer 1: A = x (f32), K=128, H=128 ----
  k_gemm_mfma<0, 4><<<gemmGrid, 256, 0, stream>>>(x, Wt1, b1, bufP, bufB, N, DIN, H1, Hp1, 2 * Hp1);
  k_agg<1, 2, 1><<<aggGrid, 256, 0, stream>>>(bufP, bufB, row_start, sorted, bufH1, N, H1);

  // ---- layer 2: A = h1 (bf16), K=128, H=76 ----
  k_gemm_mfma<1, 4><<<gemmGrid, 256, 0, stream>>>(bufH1, Wt2, b2, bufP, bufC, N, H1, H2, Hp2, 2 * Hp2);
  k_agg<1, 2, 1><<<aggGrid, 256, 0, stream>>>(bufP, bufC, row_start, sorted, bufH2, N, H2);

  // ---- layer 3: A = h2 (bf16), K=76, H=64 ----
  k_gemm_mfma<2, 3><<<gemmGrid, 256, 0, stream>>>(bufH2, Wt3, b3, bufP, bufB, N, H2, H3, Hp3, 2 * Hp3);
  k_agg<0, 1, 0><<<aggGrid, 256, 0, stream>>>(bufP, bufB, row_start, sorted, d_out, N, H3);
}

// Round 4
// 430.414 us; speedup vs baseline: 2.7578x; 1.3601x over previous
//
#include <hip/hip_runtime.h>
#include <hip/hip_bf16.h>
#include <cstdint>
#include <cstddef>

// ---------------------------------------------------------------------------
// GraphSAGE 3-layer encoder, MFMA edition + counting-sort CSR build.
// Per layer (fused): [P | Q] = A @ [Wl | Wr]  via bf16 MFMA (f32 accum)
//   P -> bf16 (gather operand), Q -> f32 (+bias)
//   out = act( inv_deg * segsum(P[src]) + Q )   (bf16 for hidden layers)
// CSR via 2-level counting sort (bucket = dst>>7): all atomics in LDS,
// all global writes (near-)sequential -> no line write-amplification.
// ---------------------------------------------------------------------------

typedef __attribute__((ext_vector_type(8))) short bf16x8;
typedef __attribute__((ext_vector_type(4))) float f32x4;

__device__ __forceinline__ short f2bf(float f) {
  uint32_t u = __builtin_bit_cast(uint32_t, f);
  u += 0x7fffu + ((u >> 16) & 1u);
  return (short)(u >> 16);
}
__device__ __forceinline__ float bflo(uint32_t u) {
  union { uint32_t i; float f; } v; v.i = u << 16; return v.f;
}
__device__ __forceinline__ float bfhi(uint32_t u) {
  union { uint32_t i; float f; } v; v.i = u & 0xffff0000u; return v.f;
}

// ---------- int64-vs-int32 edge index detection ----------
__global__ void k_detect(const int* __restrict__ ei, int* __restrict__ flag, int E) {
  int t = threadIdx.x;
  int stride = E / 4096; if (stride < 1) stride = 1;
  int found = 0;
  for (int i = t; i < 4096; i += 256) {
    long long e = (long long)i * stride;
    if (e < E && ei[2 * e + 1] != 0) found = 1;
  }
  if (found) atomicOr(flag, 1);
}

__device__ __forceinline__ int edge_val(const int* ei, int is64, size_t pos) {
  return is64 ? ei[2 * pos] : ei[pos];
}

// ============================ counting-sort CSR =============================
// bucket = dst >> 7 (128 nodes per bucket). NB <= 1024 assumed (N <= 131072).
#define GPART 256   // partition blocks

// Phase A: per-block bucket histogram (LDS), hist[g][b]
__global__ __launch_bounds__(256)
void k_bhist(const int* __restrict__ ei, const int* __restrict__ flag,
             int* __restrict__ hist, int E, int NB, int CPB) {
  __shared__ int lh[1024];
  int g = blockIdx.x, t = threadIdx.x;
  for (int b = t; b < NB; b += 256) lh[b] = 0;
  __syncthreads();
  int is64 = (*flag == 0);
  int e0 = g * CPB, e1 = min(e0 + CPB, E);
  for (int e = e0 + t; e < e1; e += 256) {
    int d = edge_val(ei, is64, (size_t)E + e);
    atomicAdd(&lh[d >> 7], 1);
  }
  __syncthreads();
  for (int b = t; b < NB; b += 256) hist[(size_t)g * NB + b] = lh[b];
}

// Phase B1: bucket totals (column sums)
__global__ void k_csum(const int* __restrict__ hist, int* __restrict__ total,
                       int NB, int G) {
  int b = blockIdx.x, t = threadIdx.x;  // 64 threads
  int s = 0;
  for (int g = t; g < G; g += 64) s += hist[(size_t)g * NB + b];
  for (int off = 32; off; off >>= 1) s += __shfl_down(s, off);
  if (t == 0) total[b] = s;
}

// Phase B2: exclusive scan of bucket totals -> bbase[0..NB]
__global__ void k_bscan(const int* __restrict__ total, int* __restrict__ bbase,
                        int NB) {
  __shared__ int sh[1024];
  int t = threadIdx.x;
  int v = (t < NB) ? total[t] : 0;
  sh[t] = v; __syncthreads();
  for (int off = 1; off < 1024; off <<= 1) {
    int x = (t >= off) ? sh[t - off] : 0;
    __syncthreads();
    sh[t] += x;
    __syncthreads();
  }
  if (t < NB) bbase[t] = sh[t] - v;
  if (t == NB - 1) bbase[NB] = sh[t];
}

// Phase B3: column exclusive prefix: hist[g][b] <- bbase[b] + sum_{g'<g}
__global__ void k_coff(int* __restrict__ hist, const int* __restrict__ bbase,
                       int NB, int G) {
  int b = blockIdx.x, t = threadIdx.x;  // 64 threads, G % 64 == 0
  int carry = bbase[b];
  for (int g0 = 0; g0 < G; g0 += 64) {
    int v = hist[(size_t)(g0 + t) * NB + b];
    int incl = v;
    #pragma unroll
    for (int off = 1; off < 64; off <<= 1) {
      int x = __shfl_up(incl, off);
      if (t >= off) incl += x;
    }
    hist[(size_t)(g0 + t) * NB + b] = carry + incl - v;
    carry += __shfl(incl, 63);
  }
}

// Phase C: place edges into bucket regions. entry = (dst&127)<<25 | src
__global__ __launch_bounds__(256)
void k_bscatter(const int* __restrict__ ei, const int* __restrict__ flag,
                const int* __restrict__ off, uint32_t* __restrict__ staging,
                int E, int NB, int CPB) {
  __shared__ int lcur[1024];
  int g = blockIdx.x, t = threadIdx.x;
  for (int b = t; b < NB; b += 256) lcur[b] = off[(size_t)g * NB + b];
  __syncthreads();
  int is64 = (*flag == 0);
  int e0 = g * CPB, e1 = min(e0 + CPB, E);
  for (int e = e0 + t; e < e1; e += 256) {
    int s = edge_val(ei, is64, (size_t)e);
    int d = edge_val(ei, is64, (size_t)E + e);
    int p = atomicAdd(&lcur[d >> 7], 1);
    staging[p] = ((uint32_t)(d & 127) << 25) | (uint32_t)s;
  }
}

// Phase D: per-bucket final sort -> sorted_src + row_start
#define LDSCAP 12288
__global__ __launch_bounds__(256)
void k_bfinal(const uint32_t* __restrict__ staging, const int* __restrict__ bbase,
              int* __restrict__ row_start, int* __restrict__ sorted_src,
              int N, int NB, int E) {
  __shared__ uint32_t ent[LDSCAP];
  __shared__ int cnt[128];
  __shared__ int pre[128];
  int b = blockIdx.x, t = threadIdx.x;
  int base = bbase[b], sz = bbase[b + 1] - base;
  int n0 = b << 7;
  if (t < 128) cnt[t] = 0;
  __syncthreads();
  bool fit = (sz <= LDSCAP);
  if (fit) {
    for (int i = t; i < sz; i += 256) {
      uint32_t u = staging[base + i];
      ent[i] = u;
      atomicAdd(&cnt[u >> 25], 1);
    }
  } else {
    for (int i = t; i < sz; i += 256)
      atomicAdd(&cnt[staging[base + i] >> 25], 1);
  }
  __syncthreads();
  if (t < 128) pre[t] = cnt[t];
  __syncthreads();
  #pragma unroll
  for (int off = 1; off < 128; off <<= 1) {
    int x = (t < 128 && t >= off) ? pre[t - off] : 0;
    __syncthreads();
    if (t < 128) pre[t] += x;
    __syncthreads();
  }
  int nn = N - n0; if (nn > 128) nn = 128;
  if (t < 128) {
    int ex = pre[t] - cnt[t];
    if (t < nn) row_start[n0 + t] = base + ex;
    cnt[t] = ex;  // becomes cursor
  }
  if (b == NB - 1 && t == 0) row_start[N] = E;
  __syncthreads();
  if (fit) {
    for (int i = t; i < sz; i += 256) {
      uint32_t u = ent[i];
      int p = atomicAdd(&cnt[u >> 25], 1);
      sorted_src[base + p] = (int)(u & 0x1FFFFFFu);
    }
  } else {
    for (int i = t; i < sz; i += 256) {
      uint32_t u = staging[base + i];
      int p = atomicAdd(&cnt[u >> 25], 1);
      sorted_src[base + p] = (int)(u & 0x1FFFFFFu);
    }
  }
}

// ---------- weight prep: Wt[c][k] (bf16, transposed, zero-padded) ----------
__global__ void k_wprep(const float* __restrict__ Wl, const float* __restrict__ Wr,
                        short* __restrict__ Wt, int K, int H, int Hp, int Kp, int NP) {
  int idx = blockIdx.x * 256 + threadIdx.x;
  if (idx >= NP * Kp) return;
  int c = idx / Kp, k = idx - c * Kp;
  float v = 0.f;
  if (k < K) {
    if (c < H) v = Wl[(size_t)k * H + c];
    else if (c >= Hp && c - Hp < H) v = Wr[(size_t)k * H + (c - Hp)];
  }
  Wt[idx] = f2bf(v);
}

// ---------- fused MFMA GEMM: [P|Q] = A @ Wt^T ----------
#define PK 136

template<int MODE, int NKS>
__global__ __launch_bounds__(256)
void k_gemm_mfma(const void* __restrict__ Av, const short* __restrict__ Wt,
                 const float* __restrict__ bias, short* __restrict__ P,
                 float* __restrict__ Q, int M, int K, int H, int Hp, int NP) {
  __shared__ short As[128][PK];
  const int Kp = NKS * 32;
  int t = threadIdx.x;
  int m0 = blockIdx.x * 128;

  if (MODE == 0) {
    const float* A = (const float*)Av;
    for (int idx = t; idx < 128 * (128 / 4); idx += 256) {
      int row = idx >> 5, c4 = (idx & 31) << 2;
      int gr = m0 + row;
      float4 v = make_float4(0.f, 0.f, 0.f, 0.f);
      if (gr < M) v = *(const float4*)(A + (size_t)gr * K + c4);
      uint2 pk;
      pk.x = (uint32_t)(uint16_t)f2bf(v.x) | ((uint32_t)(uint16_t)f2bf(v.y) << 16);
      pk.y = (uint32_t)(uint16_t)f2bf(v.z) | ((uint32_t)(uint16_t)f2bf(v.w) << 16);
      *(uint2*)&As[row][c4] = pk;
    }
  } else if (MODE == 1) {
    const short* A = (const short*)Av;
    for (int idx = t; idx < 128 * (128 / 4); idx += 256) {
      int row = idx >> 5, c4 = (idx & 31) << 2;
      int gr = m0 + row;
      uint2 v = make_uint2(0u, 0u);
      if (gr < M) v = *(const uint2*)(A + (size_t)gr * K + c4);
      *(uint2*)&As[row][c4] = v;
    }
  } else {
    const short* A = (const short*)Av;
    for (int idx = t; idx < 128 * 48; idx += 256) {
      int row = idx / 48, c2 = idx - row * 48;
      int k = c2 * 2;
      int gr = m0 + row;
      uint32_t v = 0u;
      if (gr < M && k < K) v = *(const uint32_t*)(A + (size_t)gr * K + k);
      *(uint32_t*)&As[row][k] = v;
    }
  }

  int wv = __builtin_amdgcn_readfirstlane(t >> 6);
  int lane = t & 63;
  int ncf_total = NP >> 4;
  int qd = ncf_total >> 2, rm = ncf_total & 3;
  int cf0 = wv * qd + (wv < rm ? wv : rm);
  int myncf = qd + (wv < rm ? 1 : 0);

  int lrow = lane & 15;
  int lk8 = (lane >> 4) * 8;

  bf16x8 b[4][NKS];
  #pragma unroll
  for (int cf = 0; cf < 4; cf++) {
    if (cf < myncf) {
      int col = (cf0 + cf) * 16 + lrow;
      #pragma unroll
      for (int ks = 0; ks < NKS; ks++)
        b[cf][ks] = *(const bf16x8*)(Wt + (size_t)col * Kp + ks * 32 + lk8);
    }
  }

  __syncthreads();

  for (int rf = 0; rf < 8; ++rf) {
    bf16x8 a[NKS];
    #pragma unroll
    for (int ks = 0; ks < NKS; ks++)
      a[ks] = *(const bf16x8*)&As[rf * 16 + lrow][ks * 32 + lk8];
    f32x4 acc[4];
    #pragma unroll
    for (int cf = 0; cf < 4; cf++) acc[cf] = (f32x4){0.f, 0.f, 0.f, 0.f};
    #pragma unroll
    for (int ks = 0; ks < NKS; ks++) {
      #pragma unroll
      for (int cf = 0; cf < 4; cf++) {
        if (cf < myncf)
          acc[cf] = __builtin_amdgcn_mfma_f32_16x16x32_bf16(a[ks], b[cf][ks], acc[cf], 0, 0, 0);
      }
    }
    int r0 = m0 + rf * 16 + (lane >> 4) * 4;
    #pragma unroll
    for (int cf = 0; cf < 4; cf++) {
      if (cf < myncf) {
        int c = (cf0 + cf) * 16 + lrow;
        bool isP = c < Hp;
        int cc = isP ? c : c - Hp;
        if (cc < H) {
          #pragma unroll
          for (int rg = 0; rg < 4; rg++) {
            int rr = r0 + rg;
            if (rr < M) {
              float v = acc[cf][rg];
              if (isP) P[(size_t)rr * H + cc] = f2bf(v);
              else     Q[(size_t)rr * H + cc] = v + bias[cc];
            }
          }
        }
      }
    }
  }
}

// ---------- aggregation: out = act( scale * sum_{e} bf16 P[src_e] + Q ) ------
template<int RELU, int PACK, int OUTBF16>
__global__ __launch_bounds__(256)
void k_agg(const short* __restrict__ P, const float* Q,
           const int* __restrict__ rs, const int* __restrict__ srcs,
           void* out, int N, int H) {
  int wave = threadIdx.x >> 6;
  int lane = threadIdx.x & 63;
  int node = blockIdx.x * 4 + wave;
  if (node >= N) return;
  int start = rs[node];
  int deg = rs[node + 1] - start;
  int c = lane * PACK;
  bool act = c < H;
  float a0 = 0.f, a1 = 0.f;
  const int* sp = srcs + start;

  for (int base = 0; base < deg; base += 64) {
    int cnt = deg - base; if (cnt > 64) cnt = 64;
    int myidx = (lane < cnt) ? sp[base + lane] : 0;
    int e = 0;
    int nfull = cnt & ~3;
    for (; e < nfull; e += 4) {
      int s0 = __shfl(myidx, e);
      int s1 = __shfl(myidx, e + 1);
      int s2 = __shfl(myidx, e + 2);
      int s3 = __shfl(myidx, e + 3);
      if (act) {
        if (PACK == 2) {
          uint32_t u0 = *(const uint32_t*)(P + (size_t)s0 * H + c);
          uint32_t u1 = *(const uint32_t*)(P + (size_t)s1 * H + c);
          uint32_t u2 = *(const uint32_t*)(P + (size_t)s2 * H + c);
          uint32_t u3 = *(const uint32_t*)(P + (size_t)s3 * H + c);
          a0 += bflo(u0); a1 += bfhi(u0);
          a0 += bflo(u1); a1 += bfhi(u1);
          a0 += bflo(u2); a1 += bfhi(u2);
          a0 += bflo(u3); a1 += bfhi(u3);
        } else {
          uint32_t u0 = *(const uint16_t*)(P + (size_t)s0 * H + c);
          uint32_t u1 = *(const uint16_t*)(P + (size_t)s1 * H + c);
          uint32_t u2 = *(const uint16_t*)(P + (size_t)s2 * H + c);
          uint32_t u3 = *(const uint16_t*)(P + (size_t)s3 * H + c);
          a0 += bflo(u0) + bflo(u1) + bflo(u2) + bflo(u3);
        }
      }
    }
    for (; e < cnt; ++e) {
      int s0 = __shfl(myidx, e);
      if (act) {
        if (PACK == 2) {
          uint32_t u0 = *(const uint32_t*)(P + (size_t)s0 * H + c);
          a0 += bflo(u0); a1 += bfhi(u0);
        } else {
          uint32_t u0 = *(const uint16_t*)(P + (size_t)s0 * H + c);
          a0 += bflo(u0);
        }
      }
    }
  }

  if (!act) return;
  float scale = 1.f / (float)(deg > 0 ? deg : 1);
  size_t o = (size_t)node * H + c;
  if (PACK == 2) {
    float2 q = *(const float2*)(Q + o);
    float v0 = a0 * scale + q.x;
    float v1 = a1 * scale + q.y;
    if (RELU) { v0 = fmaxf(v0, 0.f); v1 = fmaxf(v1, 0.f); }
    if (OUTBF16) {
      uint32_t pk = (uint32_t)(uint16_t)f2bf(v0) | ((uint32_t)(uint16_t)f2bf(v1) << 16);
      *(uint32_t*)((short*)out + o) = pk;
    } else {
      float2 r; r.x = v0; r.y = v1;
      *(float2*)((float*)out + o) = r;
    }
  } else {
    float v0 = a0 * scale + Q[o];
    if (RELU) v0 = fmaxf(v0, 0.f);
    if (OUTBF16) ((short*)out)[o] = f2bf(v0);
    else ((float*)out)[o] = v0;
  }
}

// ---------------------------------------------------------------------------
extern "C" void kernel_launch(void* const* d_in, const int* in_sizes, int n_in,
                              void* d_out, int out_size, void* d_ws, size_t ws_size,
                              hipStream_t stream) {
  const float* x   = (const float*)d_in[0];
  const int*   ei  = (const int*)d_in[1];
  const float* Wl1 = (const float*)d_in[2];
  const float* Wr1 = (const float*)d_in[3];
  const float* b1  = (const float*)d_in[4];
  const float* Wl2 = (const float*)d_in[5];
  const float* Wr2 = (const float*)d_in[6];
  const float* b2  = (const float*)d_in[7];
  const float* Wl3 = (const float*)d_in[8];
  const float* Wr3 = (const float*)d_in[9];
  const float* b3  = (const float*)d_in[10];

  const int DIN = 128;
  const int N  = in_sizes[0] / DIN;   // 100000
  const int E  = in_sizes[1] / 2;     // 1600000
  const int H1 = in_sizes[4];         // 128
  const int H2 = in_sizes[7];         // 76
  const int H3 = in_sizes[10];        // 64
  const int Hp1 = 128, Hp2 = 80, Hp3 = 64;
  const int Kp12 = 128, Kp3 = 96;
  const int NB = (N + 127) >> 7;      // 782
  const int G = GPART;
  const int CPB = (E + G - 1) / G;

  // ---- workspace carve ----
  char* w = (char*)d_ws;
  auto alloc = [&](size_t bytes) {
    char* p = w;
    w += (bytes + 255) & ~(size_t)255;
    return p;
  };
  short* bufP  = (short*)alloc((size_t)N * 128 * 2);
  short* bufH1 = (short*)alloc((size_t)N * 128 * 2);
  short* bufH2 = (short*)alloc((size_t)N * 80 * 2);
  float* bufB  = (float*)alloc((size_t)N * 128 * 4);
  float* bufC  = (float*)alloc((size_t)N * 80 * 4);
  short* Wt1   = (short*)alloc((size_t)256 * 128 * 2);
  short* Wt2   = (short*)alloc((size_t)160 * 128 * 2);
  short* Wt3   = (short*)alloc((size_t)128 * 96 * 2);
  int* row_start = (int*)alloc((size_t)(N + 1) * 4);
  int* hist      = (int*)alloc((size_t)G * NB * 4);
  int* total     = (int*)alloc((size_t)NB * 4);
  int* bbase     = (int*)alloc((size_t)(NB + 1) * 4);
  uint32_t* staging = (uint32_t*)alloc((size_t)E * 4);
  int* sorted    = (int*)alloc((size_t)E * 4);
  int* flag      = (int*)alloc(256);

  // ---- weight prep ----
  k_wprep<<<(256 * 128 + 255) / 256, 256, 0, stream>>>(Wl1, Wr1, Wt1, DIN, H1, Hp1, Kp12, 2 * Hp1);
  k_wprep<<<(160 * 128 + 255) / 256, 256, 0, stream>>>(Wl2, Wr2, Wt2, H1, H2, Hp2, Kp12, 2 * Hp2);
  k_wprep<<<(128 * 96 + 255) / 256, 256, 0, stream>>>(Wl3, Wr3, Wt3, H2, H3, Hp3, Kp3, 2 * Hp3);

  // ---- CSR build (counting sort) ----
  hipMemsetAsync(flag, 0, 4, stream);
  k_detect<<<1, 256, 0, stream>>>(ei, flag, E);
  k_bhist<<<G, 256, 0, stream>>>(ei, flag, hist, E, NB, CPB);
  k_csum<<<NB, 64, 0, stream>>>(hist, total, NB, G);
  k_bscan<<<1, 1024, 0, stream>>>(total, bbase, NB);
  k_coff<<<NB, 64, 0, stream>>>(hist, bbase, NB, G);
  k_bscatter<<<G, 256, 0, stream>>>(ei, flag, hist, staging, E, NB, CPB);
  k_bfinal<<<NB, 256, 0, stream>>>(staging, bbase, row_start, sorted, N, NB, E);

  int gemmGrid = (N + 127) / 128;
  int aggGrid = (N + 3) / 4;

  // ---- layer 1: A = x (f32), K=128, H=128 ----
  k_gemm_mfma<0, 4><<<gemmGrid, 256, 0, stream>>>(x, Wt1, b1, bufP, bufB, N, DIN, H1, Hp1, 2 * Hp1);
  k_agg<1, 2, 1><<<aggGrid, 256, 0, stream>>>(bufP, bufB, row_start, sorted, bufH1, N, H1);

  // ---- layer 2: A = h1 (bf16), K=128, H=76 ----
  k_gemm_mfma<1, 4><<<gemmGrid, 256, 0, stream>>>(bufH1, Wt2, b2, bufP, bufC, N, H1, H2, Hp2, 2 * Hp2);
  k_agg<1, 2, 1><<<aggGrid, 256, 0, stream>>>(bufP, bufC, row_start, sorted, bufH2, N, H2);

  // ---- layer 3: A = h2 (bf16), K=76, H=64 ----
  k_gemm_mfma<2, 3><<<gemmGrid, 256, 0, stream>>>(bufH2, Wt3, b3, bufP, bufB, N, H2, H3, Hp3, 2 * Hp3);
  k_agg<0, 1, 0><<<aggGrid, 256, 0, stream>>>(bufP, bufB, row_start, sorted, d_out, N, H3);
}

// Round 5
// 360.767 us; speedup vs baseline: 3.2902x; 1.1931x over previous
//
#include <hip/hip_runtime.h>
#include <hip/hip_bf16.h>
#include <cstdint>
#include <cstddef>

// ---------------------------------------------------------------------------
// GraphSAGE 3-layer encoder. MFMA GEMM (LDS-free, weight-stationary) +
// counting-sort CSR build + gather-mean aggregation.
// Per layer (fused): [P | Q] = A @ [Wl | Wr] via bf16 MFMA (f32 accum)
//   P -> bf16 (gather operand); Q -> bf16 (layers 1,2) / f32 (layer 3)
//   out = act( inv_deg * segsum(P[src]) + Q )
// ---------------------------------------------------------------------------

typedef __attribute__((ext_vector_type(8))) short bf16x8;
typedef __attribute__((ext_vector_type(4))) float f32x4;

__device__ __forceinline__ short f2bf(float f) {
  uint32_t u = __builtin_bit_cast(uint32_t, f);
  u += 0x7fffu + ((u >> 16) & 1u);
  return (short)(u >> 16);
}
__device__ __forceinline__ float bflo(uint32_t u) {
  union { uint32_t i; float f; } v; v.i = u << 16; return v.f;
}
__device__ __forceinline__ float bfhi(uint32_t u) {
  union { uint32_t i; float f; } v; v.i = u & 0xffff0000u; return v.f;
}

// ---------- int64-vs-int32 edge index detection ----------
__global__ void k_detect(const int* __restrict__ ei, int* __restrict__ flag, int E) {
  int t = threadIdx.x;
  int stride = E / 4096; if (stride < 1) stride = 1;
  int found = 0;
  for (int i = t; i < 4096; i += 256) {
    long long e = (long long)i * stride;
    if (e < E && ei[2 * e + 1] != 0) found = 1;
  }
  if (found) atomicOr(flag, 1);
}

__device__ __forceinline__ int edge_val(const int* ei, int is64, size_t pos) {
  return is64 ? ei[2 * pos] : ei[pos];
}

// ============================ counting-sort CSR =============================
// bucket = dst >> 7 (128 nodes per bucket). NB <= 1024 assumed.
#define GPART 256

__global__ __launch_bounds__(256)
void k_bhist(const int* __restrict__ ei, const int* __restrict__ flag,
             int* __restrict__ hist, int E, int NB, int CPB) {
  __shared__ int lh[1024];
  int g = blockIdx.x, t = threadIdx.x;
  for (int b = t; b < NB; b += 256) lh[b] = 0;
  __syncthreads();
  int is64 = (*flag == 0);
  int e0 = g * CPB, e1 = min(e0 + CPB, E);
  for (int e = e0 + t; e < e1; e += 256) {
    int d = edge_val(ei, is64, (size_t)E + e);
    atomicAdd(&lh[d >> 7], 1);
  }
  __syncthreads();
  for (int b = t; b < NB; b += 256) hist[(size_t)g * NB + b] = lh[b];
}

__global__ void k_csum(const int* __restrict__ hist, int* __restrict__ total,
                       int NB, int G) {
  int b = blockIdx.x, t = threadIdx.x;
  int s = 0;
  for (int g = t; g < G; g += 64) s += hist[(size_t)g * NB + b];
  for (int off = 32; off; off >>= 1) s += __shfl_down(s, off);
  if (t == 0) total[b] = s;
}

__global__ void k_bscan(const int* __restrict__ total, int* __restrict__ bbase,
                        int NB) {
  __shared__ int sh[1024];
  int t = threadIdx.x;
  int v = (t < NB) ? total[t] : 0;
  sh[t] = v; __syncthreads();
  for (int off = 1; off < 1024; off <<= 1) {
    int x = (t >= off) ? sh[t - off] : 0;
    __syncthreads();
    sh[t] += x;
    __syncthreads();
  }
  if (t < NB) bbase[t] = sh[t] - v;
  if (t == NB - 1) bbase[NB] = sh[t];
}

__global__ void k_coff(int* __restrict__ hist, const int* __restrict__ bbase,
                       int NB, int G) {
  int b = blockIdx.x, t = threadIdx.x;
  int carry = bbase[b];
  for (int g0 = 0; g0 < G; g0 += 64) {
    int v = hist[(size_t)(g0 + t) * NB + b];
    int incl = v;
    #pragma unroll
    for (int off = 1; off < 64; off <<= 1) {
      int x = __shfl_up(incl, off);
      if (t >= off) incl += x;
    }
    hist[(size_t)(g0 + t) * NB + b] = carry + incl - v;
    carry += __shfl(incl, 63);
  }
}

__global__ __launch_bounds__(256)
void k_bscatter(const int* __restrict__ ei, const int* __restrict__ flag,
                const int* __restrict__ off, uint32_t* __restrict__ staging,
                int E, int NB, int CPB) {
  __shared__ int lcur[1024];
  int g = blockIdx.x, t = threadIdx.x;
  for (int b = t; b < NB; b += 256) lcur[b] = off[(size_t)g * NB + b];
  __syncthreads();
  int is64 = (*flag == 0);
  int e0 = g * CPB, e1 = min(e0 + CPB, E);
  for (int e = e0 + t; e < e1; e += 256) {
    int s = edge_val(ei, is64, (size_t)e);
    int d = edge_val(ei, is64, (size_t)E + e);
    int p = atomicAdd(&lcur[d >> 7], 1);
    staging[p] = ((uint32_t)(d & 127) << 25) | (uint32_t)s;
  }
}

#define LDSCAP 12288
__global__ __launch_bounds__(256)
void k_bfinal(const uint32_t* __restrict__ staging, const int* __restrict__ bbase,
              int* __restrict__ row_start, int* __restrict__ sorted_src,
              int N, int NB, int E) {
  __shared__ uint32_t ent[LDSCAP];
  __shared__ int cnt[128];
  __shared__ int pre[128];
  int b = blockIdx.x, t = threadIdx.x;
  int base = bbase[b], sz = bbase[b + 1] - base;
  int n0 = b << 7;
  if (t < 128) cnt[t] = 0;
  __syncthreads();
  bool fit = (sz <= LDSCAP);
  if (fit) {
    for (int i = t; i < sz; i += 256) {
      uint32_t u = staging[base + i];
      ent[i] = u;
      atomicAdd(&cnt[u >> 25], 1);
    }
  } else {
    for (int i = t; i < sz; i += 256)
      atomicAdd(&cnt[staging[base + i] >> 25], 1);
  }
  __syncthreads();
  if (t < 128) pre[t] = cnt[t];
  __syncthreads();
  #pragma unroll
  for (int off = 1; off < 128; off <<= 1) {
    int x = (t < 128 && t >= off) ? pre[t - off] : 0;
    __syncthreads();
    if (t < 128) pre[t] += x;
    __syncthreads();
  }
  int nn = N - n0; if (nn > 128) nn = 128;
  if (t < 128) {
    int ex = pre[t] - cnt[t];
    if (t < nn) row_start[n0 + t] = base + ex;
    cnt[t] = ex;
  }
  if (b == NB - 1 && t == 0) row_start[N] = E;
  __syncthreads();
  if (fit) {
    for (int i = t; i < sz; i += 256) {
      uint32_t u = ent[i];
      int p = atomicAdd(&cnt[u >> 25], 1);
      sorted_src[base + p] = (int)(u & 0x1FFFFFFu);
    }
  } else {
    for (int i = t; i < sz; i += 256) {
      uint32_t u = staging[base + i];
      int p = atomicAdd(&cnt[u >> 25], 1);
      sorted_src[base + p] = (int)(u & 0x1FFFFFFu);
    }
  }
}

// ---------- weight prep: Wt[c][k] (bf16, transposed, zero-padded) ----------
__global__ void k_wprep(const float* __restrict__ Wl, const float* __restrict__ Wr,
                        short* __restrict__ Wt, int K, int H, int Hp, int Kp, int NP) {
  int idx = blockIdx.x * 256 + threadIdx.x;
  if (idx >= NP * Kp) return;
  int c = idx / Kp, k = idx - c * Kp;
  float v = 0.f;
  if (k < K) {
    if (c < H) v = Wl[(size_t)k * H + c];
    else if (c >= Hp && c - Hp < H) v = Wr[(size_t)k * H + (c - Hp)];
  }
  Wt[idx] = f2bf(v);
}

// ---------- LDS-free MFMA GEMM: [P|Q] = A @ Wt^T ----------
// MODE 0: A f32 (cvt in regs), stride lda floats. MODE 1: A bf16, stride lda.
// Block: 4 waves; wave = 16-row frags x 2 col-frags; block = 64 rows.
// grid.x = ceil(M/64); grid.y covers col-frags in chunks of 8 (4 waves x 2).
// No LDS, no barriers: waves free-run, global loads overlap MFMA.
template<int MODE, int NKS, int QBF16>
__global__ __launch_bounds__(256, 4)
void k_gemm2(const void* __restrict__ Av, const short* __restrict__ Wt,
             const float* __restrict__ bias, short* __restrict__ P,
             void* __restrict__ Qv, int M, int lda, int H, int Hp, int F) {
  const int Kp = NKS * 32;
  int t = threadIdx.x;
  int wv = t >> 6, lane = t & 63;
  int lrow = lane & 15, lk8 = (lane >> 4) * 8;
  int m0 = blockIdx.x * 64;
  int f0 = blockIdx.y * 8 + wv * 2;
  int nf = F - f0; nf = nf < 0 ? 0 : (nf > 2 ? 2 : nf);
  if (nf == 0) return;

  // B fragments + per-col metadata
  bf16x8 b[2][NKS];
  float bia[2];
  int ccol[2]; bool isPc[2]; bool cok[2];
  #pragma unroll
  for (int cf = 0; cf < 2; cf++) {
    int c = (f0 + cf) * 16 + lrow;
    bool p = c < Hp;
    int cc = p ? c : c - Hp;
    ccol[cf] = cc; isPc[cf] = p;
    cok[cf] = (cf < nf) && (cc < H);
    bia[cf] = (cok[cf] && !p) ? bias[cc] : 0.f;
    if (cf < nf) {
      const short* wp = Wt + (size_t)c * Kp + lk8;
      #pragma unroll
      for (int ks = 0; ks < NKS; ks++)
        b[cf][ks] = *(const bf16x8*)(wp + ks * 32);
    }
  }

  #pragma unroll
  for (int rf = 0; rf < 4; rf++) {
    int arow = m0 + rf * 16 + lrow;
    bool rok = arow < M;
    bf16x8 a[NKS];
    if (MODE == 0) {
      const float* ap = (const float*)Av + (size_t)arow * lda + lk8;
      #pragma unroll
      for (int ks = 0; ks < NKS; ks++) {
        if (rok) {
          float4 v0 = *(const float4*)(ap + ks * 32);
          float4 v1 = *(const float4*)(ap + ks * 32 + 4);
          bf16x8 r;
          r[0] = f2bf(v0.x); r[1] = f2bf(v0.y); r[2] = f2bf(v0.z); r[3] = f2bf(v0.w);
          r[4] = f2bf(v1.x); r[5] = f2bf(v1.y); r[6] = f2bf(v1.z); r[7] = f2bf(v1.w);
          a[ks] = r;
        } else {
          a[ks] = (bf16x8){0, 0, 0, 0, 0, 0, 0, 0};
        }
      }
    } else {
      const short* ap = (const short*)Av + (size_t)arow * lda + lk8;
      #pragma unroll
      for (int ks = 0; ks < NKS; ks++)
        a[ks] = rok ? *(const bf16x8*)(ap + ks * 32)
                    : (bf16x8){0, 0, 0, 0, 0, 0, 0, 0};
    }

    f32x4 acc[2];
    acc[0] = (f32x4){0.f, 0.f, 0.f, 0.f};
    acc[1] = (f32x4){0.f, 0.f, 0.f, 0.f};
    #pragma unroll
    for (int ks = 0; ks < NKS; ks++) {
      #pragma unroll
      for (int cf = 0; cf < 2; cf++) {
        if (cf < nf)
          acc[cf] = __builtin_amdgcn_mfma_f32_16x16x32_bf16(a[ks], b[cf][ks], acc[cf], 0, 0, 0);
      }
    }

    int rbase = m0 + rf * 16 + (lane >> 4) * 4;
    #pragma unroll
    for (int cf = 0; cf < 2; cf++) {
      if (cok[cf]) {
        #pragma unroll
        for (int rg = 0; rg < 4; rg++) {
          int rr = rbase + rg;
          if (rr < M) {
            float v = acc[cf][rg];
            if (isPc[cf]) {
              P[(size_t)rr * H + ccol[cf]] = f2bf(v);
            } else {
              v += bia[cf];
              if (QBF16) ((short*)Qv)[(size_t)rr * H + ccol[cf]] = f2bf(v);
              else       ((float*)Qv)[(size_t)rr * H + ccol[cf]] = v;
            }
          }
        }
      }
    }
  }
}

// ---------- aggregation: out = act( scale * sum_{e} bf16 P[src_e] + Q ) ------
// HSo = output row stride (>= H; pad cols untouched, consumed by zero W rows).
template<int RELU, int PACK, int OUTBF16, int QBF16>
__global__ __launch_bounds__(256)
void k_agg(const short* __restrict__ P, const void* Q,
           const int* __restrict__ rs, const int* __restrict__ srcs,
           void* out, int N, int H, int HSo) {
  int wave = threadIdx.x >> 6;
  int lane = threadIdx.x & 63;
  int node = blockIdx.x * 4 + wave;
  if (node >= N) return;
  int start = rs[node];
  int deg = rs[node + 1] - start;
  int c = lane * PACK;
  bool act = c < H;
  float a0 = 0.f, a1 = 0.f;
  const int* sp = srcs + start;

  for (int base = 0; base < deg; base += 64) {
    int cnt = deg - base; if (cnt > 64) cnt = 64;
    int myidx = (lane < cnt) ? sp[base + lane] : 0;
    int e = 0;
    int nfull = cnt & ~3;
    for (; e < nfull; e += 4) {
      int s0 = __shfl(myidx, e);
      int s1 = __shfl(myidx, e + 1);
      int s2 = __shfl(myidx, e + 2);
      int s3 = __shfl(myidx, e + 3);
      if (act) {
        if (PACK == 2) {
          uint32_t u0 = *(const uint32_t*)(P + (size_t)s0 * H + c);
          uint32_t u1 = *(const uint32_t*)(P + (size_t)s1 * H + c);
          uint32_t u2 = *(const uint32_t*)(P + (size_t)s2 * H + c);
          uint32_t u3 = *(const uint32_t*)(P + (size_t)s3 * H + c);
          a0 += bflo(u0); a1 += bfhi(u0);
          a0 += bflo(u1); a1 += bfhi(u1);
          a0 += bflo(u2); a1 += bfhi(u2);
          a0 += bflo(u3); a1 += bfhi(u3);
        } else {
          uint32_t u0 = *(const uint16_t*)(P + (size_t)s0 * H + c);
          uint32_t u1 = *(const uint16_t*)(P + (size_t)s1 * H + c);
          uint32_t u2 = *(const uint16_t*)(P + (size_t)s2 * H + c);
          uint32_t u3 = *(const uint16_t*)(P + (size_t)s3 * H + c);
          a0 += bflo(u0) + bflo(u1) + bflo(u2) + bflo(u3);
        }
      }
    }
    for (; e < cnt; ++e) {
      int s0 = __shfl(myidx, e);
      if (act) {
        if (PACK == 2) {
          uint32_t u0 = *(const uint32_t*)(P + (size_t)s0 * H + c);
          a0 += bflo(u0); a1 += bfhi(u0);
        } else {
          uint32_t u0 = *(const uint16_t*)(P + (size_t)s0 * H + c);
          a0 += bflo(u0);
        }
      }
    }
  }

  if (!act) return;
  float scale = 1.f / (float)(deg > 0 ? deg : 1);
  size_t oq = (size_t)node * H + c;
  size_t oo = (size_t)node * HSo + c;
  if (PACK == 2) {
    float q0, q1;
    if (QBF16) {
      uint32_t qu = *(const uint32_t*)((const short*)Q + oq);
      q0 = bflo(qu); q1 = bfhi(qu);
    } else {
      float2 q = *(const float2*)((const float*)Q + oq);
      q0 = q.x; q1 = q.y;
    }
    float v0 = a0 * scale + q0;
    float v1 = a1 * scale + q1;
    if (RELU) { v0 = fmaxf(v0, 0.f); v1 = fmaxf(v1, 0.f); }
    if (OUTBF16) {
      uint32_t pk = (uint32_t)(uint16_t)f2bf(v0) | ((uint32_t)(uint16_t)f2bf(v1) << 16);
      *(uint32_t*)((short*)out + oo) = pk;
    } else {
      float2 r; r.x = v0; r.y = v1;
      *(float2*)((float*)out + oo) = r;
    }
  } else {
    float q0;
    if (QBF16) q0 = bflo(*(const uint16_t*)((const short*)Q + oq));
    else       q0 = ((const float*)Q)[oq];
    float v0 = a0 * scale + q0;
    if (RELU) v0 = fmaxf(v0, 0.f);
    if (OUTBF16) ((short*)out)[oo] = f2bf(v0);
    else ((float*)out)[oo] = v0;
  }
}

// ---------------------------------------------------------------------------
extern "C" void kernel_launch(void* const* d_in, const int* in_sizes, int n_in,
                              void* d_out, int out_size, void* d_ws, size_t ws_size,
                              hipStream_t stream) {
  const float* x   = (const float*)d_in[0];
  const int*   ei  = (const int*)d_in[1];
  const float* Wl1 = (const float*)d_in[2];
  const float* Wr1 = (const float*)d_in[3];
  const float* b1  = (const float*)d_in[4];
  const float* Wl2 = (const float*)d_in[5];
  const float* Wr2 = (const float*)d_in[6];
  const float* b2  = (const float*)d_in[7];
  const float* Wl3 = (const float*)d_in[8];
  const float* Wr3 = (const float*)d_in[9];
  const float* b3  = (const float*)d_in[10];

  const int DIN = 128;
  const int N  = in_sizes[0] / DIN;   // 100000
  const int E  = in_sizes[1] / 2;     // 1600000
  const int H1 = in_sizes[4];         // 128
  const int H2 = in_sizes[7];         // 76
  const int H3 = in_sizes[10];        // 64
  const int Hp1 = 128, Hp2 = 80, Hp3 = 64;
  const int Kp12 = 128, Kp3 = 96;
  const int NB = (N + 127) >> 7;
  const int G = GPART;
  const int CPB = (E + G - 1) / G;

  // ---- workspace carve ----
  char* w = (char*)d_ws;
  auto alloc = [&](size_t bytes) {
    char* p = w;
    w += (bytes + 255) & ~(size_t)255;
    return p;
  };
  short* bufP  = (short*)alloc((size_t)N * 128 * 2);   // P (bf16)
  short* bufH1 = (short*)alloc((size_t)N * 128 * 2);   // h1 (bf16, stride 128)
  short* bufH2 = (short*)alloc((size_t)N * 96 * 2);    // h2 (bf16, stride 96=Kp3)
  short* q1    = (short*)alloc((size_t)N * 128 * 2);   // Q1 (bf16)
  short* q2    = (short*)alloc((size_t)N * 76 * 2);    // Q2 (bf16)
  float* q3    = (float*)alloc((size_t)N * 64 * 4);    // Q3 (f32)
  short* Wt1   = (short*)alloc((size_t)256 * 128 * 2);
  short* Wt2   = (short*)alloc((size_t)160 * 128 * 2);
  short* Wt3   = (short*)alloc((size_t)128 * 96 * 2);
  int* row_start = (int*)alloc((size_t)(N + 1) * 4);
  int* hist      = (int*)alloc((size_t)G * NB * 4);
  int* total     = (int*)alloc((size_t)NB * 4);
  int* bbase     = (int*)alloc((size_t)(NB + 1) * 4);
  uint32_t* staging = (uint32_t*)alloc((size_t)E * 4);
  int* sorted    = (int*)alloc((size_t)E * 4);
  int* flag      = (int*)alloc(256);

  // ---- weight prep ----
  k_wprep<<<(256 * 128 + 255) / 256, 256, 0, stream>>>(Wl1, Wr1, Wt1, DIN, H1, Hp1, Kp12, 2 * Hp1);
  k_wprep<<<(160 * 128 + 255) / 256, 256, 0, stream>>>(Wl2, Wr2, Wt2, H1, H2, Hp2, Kp12, 2 * Hp2);
  k_wprep<<<(128 * 96 + 255) / 256, 256, 0, stream>>>(Wl3, Wr3, Wt3, H2, H3, Hp3, Kp3, 2 * Hp3);

  // ---- CSR build (counting sort) ----
  hipMemsetAsync(flag, 0, 4, stream);
  k_detect<<<1, 256, 0, stream>>>(ei, flag, E);
  k_bhist<<<G, 256, 0, stream>>>(ei, flag, hist, E, NB, CPB);
  k_csum<<<NB, 64, 0, stream>>>(hist, total, NB, G);
  k_bscan<<<1, 1024, 0, stream>>>(total, bbase, NB);
  k_coff<<<NB, 64, 0, stream>>>(hist, bbase, NB, G);
  k_bscatter<<<G, 256, 0, stream>>>(ei, flag, hist, staging, E, NB, CPB);
  k_bfinal<<<NB, 256, 0, stream>>>(staging, bbase, row_start, sorted, N, NB, E);

  int gx = (N + 63) / 64;
  int aggGrid = (N + 3) / 4;

  // ---- layer 1: A = x (f32, lda=128), F=16 col-frags ----
  k_gemm2<0, 4, 1><<<dim3(gx, 2), 256, 0, stream>>>(x, Wt1, b1, bufP, q1, N, DIN, H1, Hp1, 16);
  k_agg<1, 2, 1, 1><<<aggGrid, 256, 0, stream>>>(bufP, q1, row_start, sorted, bufH1, N, H1, 128);

  // ---- layer 2: A = h1 (bf16, lda=128), F=10 ----
  k_gemm2<1, 4, 1><<<dim3(gx, 2), 256, 0, stream>>>(bufH1, Wt2, b2, bufP, q2, N, Kp12, H2, Hp2, 10);
  k_agg<1, 2, 1, 1><<<aggGrid, 256, 0, stream>>>(bufP, q2, row_start, sorted, bufH2, N, H2, 96);

  // ---- layer 3: A = h2 (bf16, lda=96), F=8 ----
  k_gemm2<1, 3, 0><<<dim3(gx, 1), 256, 0, stream>>>(bufH2, Wt3, b3, bufP, q3, N, Kp3, H3, Hp3, 8);
  k_agg<0, 1, 0, 0><<<aggGrid, 256, 0, stream>>>(bufP, q3, row_start, sorted, d_out, N, H3, 64);
}